// Round 1
// baseline (79.786 us; speedup 1.0000x reference)
//
#include <hip/hip_runtime.h>

#define NDEF 20000
#define BSES 64
#define EDIM 128
#define HDIM 128
#define KSCALE 2.8853900817779268f  // 2*log2(e): exp(2x) = exp2(KSCALE*x)

__device__ __forceinline__ float fexp2(float x) {
#if __has_builtin(__builtin_amdgcn_exp2f)
  return __builtin_amdgcn_exp2f(x);
#else
  return exp2f(x);
#endif
}
__device__ __forceinline__ float frcp(float x) {
#if __has_builtin(__builtin_amdgcn_rcpf)
  return __builtin_amdgcn_rcpf(x);
#else
  return 1.0f / x;
#endif
}

// sp'[b][h] = (sess[b]·W1[:,h] + b1[h]) * KSCALE ; also C = sum(W3) + b3
__global__ __launch_bounds__(256) void taa_k1a(
    const float* __restrict__ sess, const float* __restrict__ W1,
    const float* __restrict__ b1, const float* __restrict__ W3,
    const float* __restrict__ b3, float* __restrict__ sp_out,
    float* __restrict__ C_out) {
  int t = blockIdx.x * blockDim.x + threadIdx.x;
  if (t < BSES * HDIM) {
    int b = t >> 7, h = t & 127;
    const float* srow = sess + b * EDIM;
    float acc = 0.f;
#pragma unroll 4
    for (int e = 0; e < EDIM; ++e)
      acc = fmaf(srow[e], W1[e * HDIM + h], acc);
    sp_out[t] = (acc + b1[h]) * KSCALE;
  }
  if (t == 0) {
    float s = b3[0];
    for (int i = 0; i < HDIM; ++i) s += W3[i];
    *C_out = s;
  }
}

// tp'[n][h] = (emb[n]·W2[:,h] + b2[h]) * KSCALE, tiled: 64 n per block
__global__ __launch_bounds__(256) void taa_k1b(
    const float* __restrict__ emb, const float* __restrict__ W2,
    const float* __restrict__ b2, float* __restrict__ tp, int N) {
  __shared__ float sm[64][132];  // emb tile, padded stride (132*4=528B, 16B-aligned)
  const int nb = blockIdx.x * 64;
  for (int k = threadIdx.x; k < 64 * 32; k += 256) {
    int r = k >> 5, c4 = k & 31;
    float4 v = make_float4(0.f, 0.f, 0.f, 0.f);
    if (nb + r < N) v = ((const float4*)(emb + (size_t)(nb + r) * EDIM))[c4];
    *(float4*)&sm[r][c4 * 4] = v;
  }
  __syncthreads();
  const int h4 = (threadIdx.x & 31) * 4;  // 4 consecutive h per thread
  const int ng = threadIdx.x >> 5;        // 8 n-groups of 8 rows
  float acc[8][4];
#pragma unroll
  for (int j = 0; j < 8; ++j)
#pragma unroll
    for (int q = 0; q < 4; ++q) acc[j][q] = 0.f;
  for (int e = 0; e < EDIM; e += 4) {
    float4 w[4];
#pragma unroll
    for (int q = 0; q < 4; ++q)
      w[q] = *(const float4*)(W2 + (size_t)(e + q) * HDIM + h4);
#pragma unroll
    for (int j = 0; j < 8; ++j) {
      float4 em = *(const float4*)&sm[ng * 8 + j][e];
      acc[j][0] = fmaf(em.x, w[0].x, acc[j][0]);
      acc[j][1] = fmaf(em.x, w[0].y, acc[j][1]);
      acc[j][2] = fmaf(em.x, w[0].z, acc[j][2]);
      acc[j][3] = fmaf(em.x, w[0].w, acc[j][3]);
      acc[j][0] = fmaf(em.y, w[1].x, acc[j][0]);
      acc[j][1] = fmaf(em.y, w[1].y, acc[j][1]);
      acc[j][2] = fmaf(em.y, w[1].z, acc[j][2]);
      acc[j][3] = fmaf(em.y, w[1].w, acc[j][3]);
      acc[j][0] = fmaf(em.z, w[2].x, acc[j][0]);
      acc[j][1] = fmaf(em.z, w[2].y, acc[j][1]);
      acc[j][2] = fmaf(em.z, w[2].z, acc[j][2]);
      acc[j][3] = fmaf(em.z, w[2].w, acc[j][3]);
      acc[j][0] = fmaf(em.w, w[3].x, acc[j][0]);
      acc[j][1] = fmaf(em.w, w[3].y, acc[j][1]);
      acc[j][2] = fmaf(em.w, w[3].z, acc[j][2]);
      acc[j][3] = fmaf(em.w, w[3].w, acc[j][3]);
    }
  }
  float4 bb = *(const float4*)(b2 + h4);
#pragma unroll
  for (int j = 0; j < 8; ++j) {
    int n = nb + ng * 8 + j;
    if (n < N) {
      float4 o;
      o.x = (acc[j][0] + bb.x) * KSCALE;
      o.y = (acc[j][1] + bb.y) * KSCALE;
      o.z = (acc[j][2] + bb.z) * KSCALE;
      o.w = (acc[j][3] + bb.w) * KSCALE;
      *(float4*)(tp + (size_t)n * HDIM + h4) = o;
    }
  }
}

// Main: lane = session b (64 lanes == 64 sessions). Wave handles 4 targets.
// score[b][n] = C - 2 * sum_h w3[h] * rcp(exp2(sp'[b][h] + tp'[n][h]) + 1)
__global__ __launch_bounds__(256) void taa_k2(
    const float* __restrict__ tp, const float* __restrict__ sp,
    const float* __restrict__ w3, const float* __restrict__ Cptr,
    float* __restrict__ out, int N) {
  const int lane = threadIdx.x & 63;
  const int wave = blockIdx.x * (blockDim.x >> 6) + (threadIdx.x >> 6);
  const int n0 = wave * 4;
  if (n0 >= N) return;
  float acc[4] = {0.f, 0.f, 0.f, 0.f};
  const float* spl = sp + lane * HDIM;
  for (int c = 0; c < 4; ++c) {  // 4 h-chunks of 32
    float4 sv[8], wv[8];
#pragma unroll
    for (int j = 0; j < 8; ++j) {
      sv[j] = *(const float4*)(spl + c * 32 + j * 4);
      wv[j] = *(const float4*)(w3 + c * 32 + j * 4);  // wave-uniform
    }
#pragma unroll
    for (int i = 0; i < 4; ++i) {
      const float* tr = tp + (size_t)(n0 + i) * HDIM + c * 32;  // wave-uniform
      float4 tv[8];
#pragma unroll
      for (int j = 0; j < 8; ++j) tv[j] = ((const float4*)tr)[j];
      float a = 0.f;
#pragma unroll
      for (int j = 0; j < 8; ++j) {
        a = fmaf(wv[j].x, frcp(fexp2(sv[j].x + tv[j].x) + 1.f), a);
        a = fmaf(wv[j].y, frcp(fexp2(sv[j].y + tv[j].y) + 1.f), a);
        a = fmaf(wv[j].z, frcp(fexp2(sv[j].z + tv[j].z) + 1.f), a);
        a = fmaf(wv[j].w, frcp(fexp2(sv[j].w + tv[j].w) + 1.f), a);
      }
      acc[i] += a;
    }
  }
  const float Cv = *Cptr;
  float4 res;
  res.x = fmaf(-2.f, acc[0], Cv);
  res.y = fmaf(-2.f, acc[1], Cv);
  res.z = fmaf(-2.f, acc[2], Cv);
  res.w = fmaf(-2.f, acc[3], Cv);
  if (n0 + 3 < N) {
    *(float4*)(out + (size_t)lane * N + n0) = res;
  } else {
    float r4[4] = {res.x, res.y, res.z, res.w};
    for (int i = 0; i < 4 && n0 + i < N; ++i) out[(size_t)lane * N + n0 + i] = r4[i];
  }
}

extern "C" void kernel_launch(void* const* d_in, const int* in_sizes, int n_in,
                              void* d_out, int out_size, void* d_ws, size_t ws_size,
                              hipStream_t stream) {
  const float* sess = (const float*)d_in[0];
  const float* emb  = (const float*)d_in[1];
  const float* W1   = (const float*)d_in[2];
  const float* b1   = (const float*)d_in[3];
  const float* W2   = (const float*)d_in[4];
  const float* b2   = (const float*)d_in[5];
  const float* W3   = (const float*)d_in[6];
  const float* b3   = (const float*)d_in[7];
  float* out = (float*)d_out;
  const int B = in_sizes[0] / EDIM;   // 64
  const int N = in_sizes[1] / EDIM;   // 20000

  float* tp = (float*)d_ws;                       // N*128 floats
  float* sp = tp + (size_t)N * HDIM;              // B*128 floats
  float* Cp = sp + (size_t)B * HDIM;              // 1 float

  taa_k1a<<<(B * HDIM + 255) / 256, 256, 0, stream>>>(sess, W1, b1, W3, b3, sp, Cp);
  taa_k1b<<<(N + 63) / 64, 256, 0, stream>>>(emb, W2, b2, tp, N);
  const int waves = (N + 3) / 4;
  taa_k2<<<(waves * 64 + 255) / 256, 256, 0, stream>>>(tp, sp, W3, Cp, out, N);
}

// Round 2
// 66.587 us; speedup vs baseline: 1.1982x; 1.1982x over previous
//
#include <hip/hip_runtime.h>

#define BSES 64
#define EDIM 128
#define HDIM 128
#define KSCALE 2.8853900817779268f  // 2*log2(e): exp(2x) = exp2(KSCALE*x)

__device__ __forceinline__ float fexp2(float x) {
#if __has_builtin(__builtin_amdgcn_exp2f)
  return __builtin_amdgcn_exp2f(x);
#else
  return exp2f(x);
#endif
}
__device__ __forceinline__ float frcp(float x) {
#if __has_builtin(__builtin_amdgcn_rcpf)
  return __builtin_amdgcn_rcpf(x);
#else
  return 1.0f / x;
#endif
}

// spT[h][b] = (sess[b]·W1[:,h] + b1[h]) * KSCALE  (TRANSPOSED for coalesced k2
// reads); also C = sum(W3) + b3.
__global__ __launch_bounds__(256) void taa_k1a(
    const float* __restrict__ sess, const float* __restrict__ W1,
    const float* __restrict__ b1, const float* __restrict__ W3,
    const float* __restrict__ b3, float* __restrict__ spT,
    float* __restrict__ C_out) {
  int t = blockIdx.x * blockDim.x + threadIdx.x;
  if (t < BSES * HDIM) {
    int b = t >> 7, h = t & 127;
    const float* srow = sess + b * EDIM;
    float acc = 0.f;
#pragma unroll 4
    for (int e = 0; e < EDIM; ++e)
      acc = fmaf(srow[e], W1[e * HDIM + h], acc);
    spT[h * BSES + b] = (acc + b1[h]) * KSCALE;
  }
  if (t == 0) {
    float s = b3[0];
    for (int i = 0; i < HDIM; ++i) s += W3[i];
    *C_out = s;
  }
}

// tp'[n][h] = (emb[n]·W2[:,h] + b2[h]) * KSCALE.
// 32 rows per block -> 625 blocks. Thread = (4 rows) x (4 h).
__global__ __launch_bounds__(256) void taa_k1b(
    const float* __restrict__ emb, const float* __restrict__ W2,
    const float* __restrict__ b2, float* __restrict__ tp, int N) {
  __shared__ float sm[32][132];  // 32-row emb tile, padded stride
  const int nb = blockIdx.x * 32;
  for (int k = threadIdx.x; k < 32 * 32; k += 256) {
    int r = k >> 5, c4 = k & 31;
    float4 v = make_float4(0.f, 0.f, 0.f, 0.f);
    if (nb + r < N) v = ((const float4*)(emb + (size_t)(nb + r) * EDIM))[c4];
    *(float4*)&sm[r][c4 * 4] = v;
  }
  __syncthreads();
  const int h4 = (threadIdx.x & 31) * 4;  // 4 consecutive h
  const int rg = threadIdx.x >> 5;        // 8 groups of 4 rows
  float acc[4][4];
#pragma unroll
  for (int j = 0; j < 4; ++j)
#pragma unroll
    for (int q = 0; q < 4; ++q) acc[j][q] = 0.f;
  for (int e = 0; e < EDIM; e += 4) {
    float4 w[4];
#pragma unroll
    for (int q = 0; q < 4; ++q)
      w[q] = *(const float4*)(W2 + (size_t)(e + q) * HDIM + h4);
#pragma unroll
    for (int j = 0; j < 4; ++j) {
      float4 em = *(const float4*)&sm[rg * 4 + j][e];
      acc[j][0] = fmaf(em.x, w[0].x, acc[j][0]);
      acc[j][1] = fmaf(em.x, w[0].y, acc[j][1]);
      acc[j][2] = fmaf(em.x, w[0].z, acc[j][2]);
      acc[j][3] = fmaf(em.x, w[0].w, acc[j][3]);
      acc[j][0] = fmaf(em.y, w[1].x, acc[j][0]);
      acc[j][1] = fmaf(em.y, w[1].y, acc[j][1]);
      acc[j][2] = fmaf(em.y, w[1].z, acc[j][2]);
      acc[j][3] = fmaf(em.y, w[1].w, acc[j][3]);
      acc[j][0] = fmaf(em.z, w[2].x, acc[j][0]);
      acc[j][1] = fmaf(em.z, w[2].y, acc[j][1]);
      acc[j][2] = fmaf(em.z, w[2].z, acc[j][2]);
      acc[j][3] = fmaf(em.z, w[2].w, acc[j][3]);
      acc[j][0] = fmaf(em.w, w[3].x, acc[j][0]);
      acc[j][1] = fmaf(em.w, w[3].y, acc[j][1]);
      acc[j][2] = fmaf(em.w, w[3].z, acc[j][2]);
      acc[j][3] = fmaf(em.w, w[3].w, acc[j][3]);
    }
  }
  float4 bb = *(const float4*)(b2 + h4);
#pragma unroll
  for (int j = 0; j < 4; ++j) {
    int n = nb + rg * 4 + j;
    if (n < N) {
      float4 o;
      o.x = (acc[j][0] + bb.x) * KSCALE;
      o.y = (acc[j][1] + bb.y) * KSCALE;
      o.z = (acc[j][2] + bb.z) * KSCALE;
      o.w = (acc[j][3] + bb.w) * KSCALE;
      *(float4*)(tp + (size_t)n * HDIM + h4) = o;
    }
  }
}

// Main: lane = session b. Wave handles 4 targets; h chunked by 16 to keep
// VGPR <= 64 (8 waves/SIMD). spT reads coalesced; w3/C scalar (uniform idx).
// score[b][n] = C - 2 * sum_h w3[h] * rcp(exp2(spT[h][b] + tp'[n][h]) + 1)
__global__ __launch_bounds__(256) void taa_k2(
    const float* __restrict__ tp, const float* __restrict__ spT,
    const float* __restrict__ w3, const float* __restrict__ Cptr,
    float* __restrict__ out, int N) {
  const int lane = threadIdx.x & 63;
  const int wave = blockIdx.x * (blockDim.x >> 6) + (threadIdx.x >> 6);
  const int n0 = wave * 4;
  if (n0 >= N) return;
  float a0a = 0.f, a0b = 0.f, a1a = 0.f, a1b = 0.f;
  float a2a = 0.f, a2b = 0.f, a3a = 0.f, a3b = 0.f;
  for (int c = 0; c < HDIM; c += 16) {
    float spc[16];
#pragma unroll
    for (int k = 0; k < 16; ++k) spc[k] = spT[(c + k) * BSES + lane];  // coalesced
    float wsc[16];
#pragma unroll
    for (int k = 0; k < 16; ++k) wsc[k] = w3[c + k];  // uniform -> s_load
    const float* tr = tp + (size_t)n0 * HDIM + c;
#define DO_TARGET(i, AA, AB)                                              \
    {                                                                     \
      const float4* t4 = (const float4*)(tr + (i) * HDIM);                \
      float4 v0 = t4[0], v1 = t4[1], v2 = t4[2], v3 = t4[3];              \
      AA = fmaf(wsc[0], frcp(fexp2(spc[0] + v0.x) + 1.f), AA);            \
      AB = fmaf(wsc[1], frcp(fexp2(spc[1] + v0.y) + 1.f), AB);            \
      AA = fmaf(wsc[2], frcp(fexp2(spc[2] + v0.z) + 1.f), AA);            \
      AB = fmaf(wsc[3], frcp(fexp2(spc[3] + v0.w) + 1.f), AB);            \
      AA = fmaf(wsc[4], frcp(fexp2(spc[4] + v1.x) + 1.f), AA);            \
      AB = fmaf(wsc[5], frcp(fexp2(spc[5] + v1.y) + 1.f), AB);            \
      AA = fmaf(wsc[6], frcp(fexp2(spc[6] + v1.z) + 1.f), AA);            \
      AB = fmaf(wsc[7], frcp(fexp2(spc[7] + v1.w) + 1.f), AB);            \
      AA = fmaf(wsc[8], frcp(fexp2(spc[8] + v2.x) + 1.f), AA);            \
      AB = fmaf(wsc[9], frcp(fexp2(spc[9] + v2.y) + 1.f), AB);            \
      AA = fmaf(wsc[10], frcp(fexp2(spc[10] + v2.z) + 1.f), AA);          \
      AB = fmaf(wsc[11], frcp(fexp2(spc[11] + v2.w) + 1.f), AB);          \
      AA = fmaf(wsc[12], frcp(fexp2(spc[12] + v3.x) + 1.f), AA);          \
      AB = fmaf(wsc[13], frcp(fexp2(spc[13] + v3.y) + 1.f), AB);          \
      AA = fmaf(wsc[14], frcp(fexp2(spc[14] + v3.z) + 1.f), AA);          \
      AB = fmaf(wsc[15], frcp(fexp2(spc[15] + v3.w) + 1.f), AB);          \
    }
    DO_TARGET(0, a0a, a0b)
    DO_TARGET(1, a1a, a1b)
    DO_TARGET(2, a2a, a2b)
    DO_TARGET(3, a3a, a3b)
#undef DO_TARGET
  }
  const float Cv = *Cptr;  // uniform -> s_load
  float4 res;
  res.x = fmaf(-2.f, a0a + a0b, Cv);
  res.y = fmaf(-2.f, a1a + a1b, Cv);
  res.z = fmaf(-2.f, a2a + a2b, Cv);
  res.w = fmaf(-2.f, a3a + a3b, Cv);
  if (n0 + 3 < N) {
    *(float4*)(out + (size_t)lane * N + n0) = res;
  } else {
    float r4[4] = {res.x, res.y, res.z, res.w};
    for (int i = 0; i < 4 && n0 + i < N; ++i) out[(size_t)lane * N + n0 + i] = r4[i];
  }
}

extern "C" void kernel_launch(void* const* d_in, const int* in_sizes, int n_in,
                              void* d_out, int out_size, void* d_ws, size_t ws_size,
                              hipStream_t stream) {
  const float* sess = (const float*)d_in[0];
  const float* emb  = (const float*)d_in[1];
  const float* W1   = (const float*)d_in[2];
  const float* b1   = (const float*)d_in[3];
  const float* W2   = (const float*)d_in[4];
  const float* b2   = (const float*)d_in[5];
  const float* W3   = (const float*)d_in[6];
  const float* b3   = (const float*)d_in[7];
  float* out = (float*)d_out;
  const int B = in_sizes[0] / EDIM;   // 64
  const int N = in_sizes[1] / EDIM;   // 20000

  float* tp  = (float*)d_ws;                      // N*128 floats
  float* spT = tp + (size_t)N * HDIM;             // 128*64 floats (transposed)
  float* Cp  = spT + (size_t)HDIM * BSES;         // 1 float

  taa_k1a<<<(B * HDIM + 255) / 256, 256, 0, stream>>>(sess, W1, b1, W3, b3, spT, Cp);
  taa_k1b<<<(N + 31) / 32, 256, 0, stream>>>(emb, W2, b2, tp, N);
  const int waves = (N + 3) / 4;
  taa_k2<<<(waves * 64 + 255) / 256, 256, 0, stream>>>(tp, spT, W3, Cp, out, N);
}

// Round 3
// 50.778 us; speedup vs baseline: 1.5713x; 1.3113x over previous
//
#include <hip/hip_runtime.h>

#define BSES 64
#define EDIM 128
#define HDIM 128
#define KSCALE 2.8853900817779268f  // 2*log2(e): exp(2x) = exp2(KSCALE*x)

__device__ __forceinline__ float fexp2(float x) {
#if __has_builtin(__builtin_amdgcn_exp2f)
  return __builtin_amdgcn_exp2f(x);
#else
  return exp2f(x);
#endif
}
__device__ __forceinline__ float frcp(float x) {
#if __has_builtin(__builtin_amdgcn_rcpf)
  return __builtin_amdgcn_rcpf(x);
#else
  return 1.0f / x;
#endif
}

// Fused projections. Blocks [0, nbTP): etp[n][h] = exp2((emb[n]·W2[:,h]+b2[h])*K)
// (32 rows per block). Blocks [nbTP, ...): espT[h][b] = exp2((sess[b]·W1[:,h]+b1[h])*K)
// transposed for coalesced k2 reads; plus C = sum(W3)+b3.
__global__ __launch_bounds__(256) void taa_k1(
    const float* __restrict__ sess, const float* __restrict__ W1,
    const float* __restrict__ b1, const float* __restrict__ emb,
    const float* __restrict__ W2, const float* __restrict__ b2,
    const float* __restrict__ W3, const float* __restrict__ b3,
    float* __restrict__ etp, float* __restrict__ espT,
    float* __restrict__ C_out, int N, int nbTP) {
  if ((int)blockIdx.x < nbTP) {
    __shared__ float sm[32][132];  // emb tile, padded stride
    const int nb = blockIdx.x * 32;
    for (int k = threadIdx.x; k < 32 * 32; k += 256) {
      int r = k >> 5, c4 = k & 31;
      float4 v = make_float4(0.f, 0.f, 0.f, 0.f);
      if (nb + r < N) v = ((const float4*)(emb + (size_t)(nb + r) * EDIM))[c4];
      *(float4*)&sm[r][c4 * 4] = v;
    }
    __syncthreads();
    const int h4 = (threadIdx.x & 31) * 4;
    const int rg = threadIdx.x >> 5;
    float acc[4][4];
#pragma unroll
    for (int j = 0; j < 4; ++j)
#pragma unroll
      for (int q = 0; q < 4; ++q) acc[j][q] = 0.f;
    for (int e = 0; e < EDIM; e += 4) {
      float4 w[4];
#pragma unroll
      for (int q = 0; q < 4; ++q)
        w[q] = *(const float4*)(W2 + (size_t)(e + q) * HDIM + h4);
#pragma unroll
      for (int j = 0; j < 4; ++j) {
        float4 em = *(const float4*)&sm[rg * 4 + j][e];
        acc[j][0] = fmaf(em.x, w[0].x, acc[j][0]);
        acc[j][1] = fmaf(em.x, w[0].y, acc[j][1]);
        acc[j][2] = fmaf(em.x, w[0].z, acc[j][2]);
        acc[j][3] = fmaf(em.x, w[0].w, acc[j][3]);
        acc[j][0] = fmaf(em.y, w[1].x, acc[j][0]);
        acc[j][1] = fmaf(em.y, w[1].y, acc[j][1]);
        acc[j][2] = fmaf(em.y, w[1].z, acc[j][2]);
        acc[j][3] = fmaf(em.y, w[1].w, acc[j][3]);
        acc[j][0] = fmaf(em.z, w[2].x, acc[j][0]);
        acc[j][1] = fmaf(em.z, w[2].y, acc[j][1]);
        acc[j][2] = fmaf(em.z, w[2].z, acc[j][2]);
        acc[j][3] = fmaf(em.z, w[2].w, acc[j][3]);
        acc[j][0] = fmaf(em.w, w[3].x, acc[j][0]);
        acc[j][1] = fmaf(em.w, w[3].y, acc[j][1]);
        acc[j][2] = fmaf(em.w, w[3].z, acc[j][2]);
        acc[j][3] = fmaf(em.w, w[3].w, acc[j][3]);
      }
    }
    float4 bb = *(const float4*)(b2 + h4);
#pragma unroll
    for (int j = 0; j < 4; ++j) {
      int n = nb + rg * 4 + j;
      if (n < N) {
        float4 o;
        o.x = fexp2((acc[j][0] + bb.x) * KSCALE);
        o.y = fexp2((acc[j][1] + bb.y) * KSCALE);
        o.z = fexp2((acc[j][2] + bb.z) * KSCALE);
        o.w = fexp2((acc[j][3] + bb.w) * KSCALE);
        *(float4*)(etp + (size_t)n * HDIM + h4) = o;
      }
    }
  } else {
    int t = ((int)blockIdx.x - nbTP) * 256 + threadIdx.x;
    if (t < BSES * HDIM) {
      int b = t >> 7, h = t & 127;
      const float* srow = sess + b * EDIM;
      float acc = 0.f;
#pragma unroll 4
      for (int e = 0; e < EDIM; ++e)
        acc = fmaf(srow[e], W1[e * HDIM + h], acc);
      espT[h * BSES + b] = fexp2((acc + b1[h]) * KSCALE);
    }
    if (t == 0) {
      float s = b3[0];
      for (int i = 0; i < HDIM; ++i) s += W3[i];
      *C_out = s;
    }
  }
}

// Main: lane = session b. Wave handles 4 targets; h chunked by 16.
// tanh(x) = 1 - 2/(exp2(K*x)+1); exp2 split: exp2(sp'+tp') = esp*etp.
// score[b][n] = C - 2 * sum_h w3[h] * rcp(fma(espT[h][b], etp[n][h], 1))
__global__ __launch_bounds__(256) void taa_k2(
    const float* __restrict__ etp, const float* __restrict__ espT,
    const float* __restrict__ w3, const float* __restrict__ Cptr,
    float* __restrict__ out, int N) {
  const int lane = threadIdx.x & 63;
  const int wave = blockIdx.x * (blockDim.x >> 6) + (threadIdx.x >> 6);
  const int n0 = wave * 4;
  if (n0 >= N) return;
  float a0a = 0.f, a0b = 0.f, a1a = 0.f, a1b = 0.f;
  float a2a = 0.f, a2b = 0.f, a3a = 0.f, a3b = 0.f;
  for (int c = 0; c < HDIM; c += 16) {
    float spc[16];
#pragma unroll
    for (int k = 0; k < 16; ++k) spc[k] = espT[(c + k) * BSES + lane];  // coalesced
    float wsc[16];
#pragma unroll
    for (int k = 0; k < 16; ++k) wsc[k] = w3[c + k];  // uniform -> s_load
    const float* tr = etp + (size_t)n0 * HDIM + c;
#define DO_TARGET(i, AA, AB)                                             \
    {                                                                    \
      const float4* t4 = (const float4*)(tr + (i) * HDIM);               \
      float4 v0 = t4[0], v1 = t4[1], v2 = t4[2], v3 = t4[3];             \
      AA = fmaf(wsc[0], frcp(fmaf(spc[0], v0.x, 1.f)), AA);              \
      AB = fmaf(wsc[1], frcp(fmaf(spc[1], v0.y, 1.f)), AB);              \
      AA = fmaf(wsc[2], frcp(fmaf(spc[2], v0.z, 1.f)), AA);              \
      AB = fmaf(wsc[3], frcp(fmaf(spc[3], v0.w, 1.f)), AB);              \
      AA = fmaf(wsc[4], frcp(fmaf(spc[4], v1.x, 1.f)), AA);              \
      AB = fmaf(wsc[5], frcp(fmaf(spc[5], v1.y, 1.f)), AB);              \
      AA = fmaf(wsc[6], frcp(fmaf(spc[6], v1.z, 1.f)), AA);              \
      AB = fmaf(wsc[7], frcp(fmaf(spc[7], v1.w, 1.f)), AB);              \
      AA = fmaf(wsc[8], frcp(fmaf(spc[8], v2.x, 1.f)), AA);              \
      AB = fmaf(wsc[9], frcp(fmaf(spc[9], v2.y, 1.f)), AB);              \
      AA = fmaf(wsc[10], frcp(fmaf(spc[10], v2.z, 1.f)), AA);            \
      AB = fmaf(wsc[11], frcp(fmaf(spc[11], v2.w, 1.f)), AB);            \
      AA = fmaf(wsc[12], frcp(fmaf(spc[12], v3.x, 1.f)), AA);            \
      AB = fmaf(wsc[13], frcp(fmaf(spc[13], v3.y, 1.f)), AB);            \
      AA = fmaf(wsc[14], frcp(fmaf(spc[14], v3.z, 1.f)), AA);            \
      AB = fmaf(wsc[15], frcp(fmaf(spc[15], v3.w, 1.f)), AB);            \
    }
    DO_TARGET(0, a0a, a0b)
    DO_TARGET(1, a1a, a1b)
    DO_TARGET(2, a2a, a2b)
    DO_TARGET(3, a3a, a3b)
#undef DO_TARGET
  }
  const float Cv = *Cptr;  // uniform -> s_load
  float4 res;
  res.x = fmaf(-2.f, a0a + a0b, Cv);
  res.y = fmaf(-2.f, a1a + a1b, Cv);
  res.z = fmaf(-2.f, a2a + a2b, Cv);
  res.w = fmaf(-2.f, a3a + a3b, Cv);
  if (n0 + 3 < N) {
    *(float4*)(out + (size_t)lane * N + n0) = res;
  } else {
    float r4[4] = {res.x, res.y, res.z, res.w};
    for (int i = 0; i < 4 && n0 + i < N; ++i) out[(size_t)lane * N + n0 + i] = r4[i];
  }
}

extern "C" void kernel_launch(void* const* d_in, const int* in_sizes, int n_in,
                              void* d_out, int out_size, void* d_ws, size_t ws_size,
                              hipStream_t stream) {
  const float* sess = (const float*)d_in[0];
  const float* emb  = (const float*)d_in[1];
  const float* W1   = (const float*)d_in[2];
  const float* b1   = (const float*)d_in[3];
  const float* W2   = (const float*)d_in[4];
  const float* b2   = (const float*)d_in[5];
  const float* W3   = (const float*)d_in[6];
  const float* b3   = (const float*)d_in[7];
  float* out = (float*)d_out;
  const int B = in_sizes[0] / EDIM;   // 64
  const int N = in_sizes[1] / EDIM;   // 20000

  float* etp  = (float*)d_ws;                     // N*128 floats
  float* espT = etp + (size_t)N * HDIM;           // 128*64 floats (transposed)
  float* Cp   = espT + (size_t)HDIM * BSES;       // 1 float

  const int nbTP = (N + 31) / 32;                 // 625
  const int nbSP = (B * HDIM + 255) / 256;        // 32
  taa_k1<<<nbTP + nbSP, 256, 0, stream>>>(sess, W1, b1, emb, W2, b2, W3, b3,
                                          etp, espT, Cp, N, nbTP);
  const int waves = (N + 3) / 4;
  taa_k2<<<(waves * 64 + 255) / 256, 256, 0, stream>>>(etp, espT, W3, Cp, out, N);
}